// Round 1
// baseline (394.289 us; speedup 1.0000x reference)
//
#include <hip/hip_runtime.h>
#include <hip/hip_bf16.h>
#include <math.h>

typedef __bf16 bf16;
typedef __bf16 bf16x8 __attribute__((ext_vector_type(8)));
typedef __bf16 bf16x4v __attribute__((ext_vector_type(4)));
typedef float f32x4 __attribute__((ext_vector_type(4)));

#define GLD16(gp, lp) __builtin_amdgcn_global_load_lds( \
    (__attribute__((address_space(1))) void*)(void*)(gp), \
    (__attribute__((address_space(3))) void*)(lp), 16, 0, 0)

#define L_SEQ 2048
#define D_MODEL 2048
#define QKV_N 3072
#define HD 128
#define SM_SCALE 0.08838834764831843f   // 1/sqrt(128)

// ---------------------------------------------------------------------------
// elementwise fp32 -> bf16 cast (4 elems/thread)
// ---------------------------------------------------------------------------
__global__ __launch_bounds__(256) void cast_f32_bf16(const float* __restrict__ src,
                                                     bf16* __restrict__ dst, int n) {
    int i = blockIdx.x * 256 + threadIdx.x;
    int idx = i * 4;
    if (idx >= n) return;
    float4 f = *(const float4*)(src + idx);
    bf16x4v o;
    o.x = (bf16)f.x; o.y = (bf16)f.y; o.z = (bf16)f.z; o.w = (bf16)f.w;
    *(bf16x4v*)(dst + idx) = o;
}

// ---------------------------------------------------------------------------
// tiled transpose-cast: dst[c][r] = (bf16) src[r][c].  32x32 tiles.
// grid: (cols/32, rows/32, z);  block: (32, 8)
// ---------------------------------------------------------------------------
__global__ __launch_bounds__(256) void transpose_cast(const float* __restrict__ src, long ld_src,
                                                      bf16* __restrict__ dst, long ld_dst,
                                                      long zsrc, long zdst) {
    __shared__ float tile[32][33];
    src += (long)blockIdx.z * zsrc;
    dst += (long)blockIdx.z * zdst;
    int tx = threadIdx.x, ty = threadIdx.y;
    long c  = blockIdx.x * 32 + tx;
    long r0 = blockIdx.y * 32;
#pragma unroll
    for (int i = 0; i < 4; ++i)
        tile[ty + i * 8][tx] = src[(r0 + ty + i * 8) * ld_src + c];
    __syncthreads();
    long c0 = blockIdx.x * 32;
#pragma unroll
    for (int i = 0; i < 4; ++i)
        dst[(c0 + ty + i * 8) * ld_dst + r0 + tx] = (bf16)tile[tx][ty + i * 8];
}

// ---------------------------------------------------------------------------
// GEMM: C[M][N] fp32 = A[M][K] bf16 (row-major) x Bt[N][K] bf16 (B transposed)
// 128x128 tile / block, 4 waves, 64x64 per wave, 16x16x32 bf16 MFMA, BK=32.
// ---------------------------------------------------------------------------
__global__ __launch_bounds__(256) void gemm_bt(const bf16* __restrict__ A,
                                               const bf16* __restrict__ Bt,
                                               float* __restrict__ C,
                                               int M, int N, int K) {
    __shared__ __align__(16) bf16 As[128 * 32];
    __shared__ __align__(16) bf16 Bs[128 * 32];
    const int tid = threadIdx.x;
    const int wid = tid >> 6, lane = tid & 63;
    const int quad = lane >> 4, l15 = lane & 15;
    const int wm = wid & 1, wn = wid >> 1;
    const long m0 = (long)blockIdx.y * 128, n0 = (long)blockIdx.x * 128;

    const int srow = wid * 32 + (lane >> 2);   // staging row within 128-tile
    const int scol = (lane & 3) * 8;           // staging col (elems)

    f32x4 acc[4][4];
#pragma unroll
    for (int i = 0; i < 4; ++i)
#pragma unroll
        for (int j = 0; j < 4; ++j) acc[i][j] = (f32x4){0.f, 0.f, 0.f, 0.f};

    const bf16* Ap  = A  + (m0 + srow) * K + scol;
    const bf16* Ap2 = Ap + (long)16 * K;
    const bf16* Bp  = Bt + (n0 + srow) * K + scol;
    const bf16* Bp2 = Bp + (long)16 * K;
    bf16* lA  = &As[(wid * 32) * 32];
    bf16* lA2 = &As[(wid * 32 + 16) * 32];
    bf16* lB  = &Bs[(wid * 32) * 32];
    bf16* lB2 = &Bs[(wid * 32 + 16) * 32];

    for (int k0 = 0; k0 < K; k0 += 32) {
        GLD16(Ap + k0, lA);
        GLD16(Ap2 + k0, lA2);
        GLD16(Bp + k0, lB);
        GLD16(Bp2 + k0, lB2);
        __syncthreads();
        bf16x8 af[4], bfr[4];
#pragma unroll
        for (int i = 0; i < 4; ++i)
            af[i] = *(const bf16x8*)&As[(wm * 64 + i * 16 + l15) * 32 + quad * 8];
#pragma unroll
        for (int j = 0; j < 4; ++j)
            bfr[j] = *(const bf16x8*)&Bs[(wn * 64 + j * 16 + l15) * 32 + quad * 8];
#pragma unroll
        for (int i = 0; i < 4; ++i)
#pragma unroll
            for (int j = 0; j < 4; ++j)
                acc[i][j] = __builtin_amdgcn_mfma_f32_16x16x32_bf16(af[i], bfr[j], acc[i][j], 0, 0, 0);
        __syncthreads();
    }
#pragma unroll
    for (int i = 0; i < 4; ++i)
#pragma unroll
        for (int j = 0; j < 4; ++j) {
            long m = m0 + wm * 64 + i * 16 + quad * 4;
            long n = n0 + wn * 64 + j * 16 + l15;
#pragma unroll
            for (int r = 0; r < 4; ++r)
                C[(m + r) * (long)N + n] = acc[i][j][r];
        }
}

// ---------------------------------------------------------------------------
// RoPE (half-truncate) + split of proj into Q [16][L][128] and K [4][L][128].
// One thread per (l, head<20, d<64) rotation pair.
// ---------------------------------------------------------------------------
__global__ __launch_bounds__(256) void rope_split(const float* __restrict__ proj,
                                                  bf16* __restrict__ Qb,
                                                  bf16* __restrict__ Kb) {
    const int idx = blockIdx.x * 256 + threadIdx.x;   // L*20*64 total, exact
    const int d = idx & 63;
    const int head = (idx >> 6) % 20;
    const int l = idx / (64 * 20);
    const long basecol = head < 16 ? (long)head * 128 : 2048L + (long)(head - 16) * 128;
    const float x1 = proj[(long)l * QKV_N + basecol + d];
    const float x2 = proj[(long)l * QKV_N + basecol + d + 64];
    float o1, o2;
    if (d < 32) {
        const float t = (float)d / 31.0f;
        const float freq = powf(1.0f / 1024.0f, t);
        const float th = (float)l * freq;
        const float c = cosf(th), s = sinf(th);
        o1 = x1 * c + x2 * s;
        o2 = x2 * c - x1 * s;
    } else {  // zero freqs -> identity
        o1 = x1; o2 = x2;
    }
    bf16* dst = head < 16 ? Qb + (long)head * L_SEQ * HD : Kb + (long)(head - 16) * L_SEQ * HD;
    dst[(long)l * HD + d] = (bf16)o1;
    dst[(long)l * HD + d + 64] = (bf16)o2;
}

// ---------------------------------------------------------------------------
// Flash-style GQA attention with inverted causal/window mask + sink logit.
// valid(q,k) = (k > q) || (k <= q-1024).  Softmax init: m=sink, l=1.
// Block: 256 thr (4 waves), one (head hq, 64-row q-tile).  64x64 K-tiles.
// ---------------------------------------------------------------------------
__global__ __launch_bounds__(256) void attn_kernel(const bf16* __restrict__ Qb,
                                                   const bf16* __restrict__ Kb,
                                                   const bf16* __restrict__ Vtb,
                                                   const float* __restrict__ sink,
                                                   bf16* __restrict__ Ob) {
    __shared__ __align__(16) bf16 Qs[64 * 128];
    __shared__ __align__(16) bf16 Ks[64 * 128];
    __shared__ __align__(16) bf16 Vts[128 * 64];   // [hd][kseq]
    __shared__ __align__(16) bf16 Ps[64 * 64];
    __shared__ float wmaxs[128];
    __shared__ float wsums[128];
    __shared__ float mst[64];
    __shared__ float lst[64];

    const int qt = blockIdx.x, hq = blockIdx.y, h = hq >> 2;
    const int q0 = qt * 64;
    const int tid = threadIdx.x;
    const int wid = tid >> 6, lane = tid & 63;
    const int quad = lane >> 4, l15 = lane & 15;
    const int wm = wid & 1, wn = wid >> 1;

    const bf16* Qg = Qb + (long)hq * L_SEQ * HD;
    const bf16* Kg = Kb + (long)h * L_SEQ * HD;
    const bf16* Vg = Vtb + (long)h * HD * L_SEQ;

    // stage Q tile (64x128 bf16)
#pragma unroll
    for (int i = 0; i < 4; ++i) {
        int r = wid * 16 + i * 4;
        GLD16(Qg + (long)(q0 + r + quad) * HD + l15 * 8, &Qs[r * HD]);
    }
    if (tid < 64) { mst[tid] = sink[hq]; lst[tid] = 1.0f; }

    f32x4 oacc[2][4];
#pragma unroll
    for (int i = 0; i < 2; ++i)
#pragma unroll
        for (int j = 0; j < 4; ++j) oacc[i][j] = (f32x4){0.f, 0.f, 0.f, 0.f};
    __syncthreads();

    for (int kt = 0; kt < L_SEQ / 64; ++kt) {
        if (!((kt >= qt) || (qt - kt >= 16))) continue;   // fully-masked tile
        const int k0 = kt * 64;
        // stage K tile (64x128) and V^T tile (128x64)
#pragma unroll
        for (int i = 0; i < 4; ++i) {
            int r = wid * 16 + i * 4;
            GLD16(Kg + (long)(k0 + r + quad) * HD + l15 * 8, &Ks[r * HD]);
        }
#pragma unroll
        for (int i = 0; i < 4; ++i) {
            int r = wid * 32 + i * 8;
            GLD16(Vg + (long)(r + (lane >> 3)) * L_SEQ + k0 + (lane & 7) * 8, &Vts[r * 64]);
        }
        __syncthreads();   // b1: tiles staged

        // S = Q K^T  (wave computes 32x32)
        f32x4 sacc[2][2];
#pragma unroll
        for (int i = 0; i < 2; ++i)
#pragma unroll
            for (int j = 0; j < 2; ++j) sacc[i][j] = (f32x4){0.f, 0.f, 0.f, 0.f};
#pragma unroll
        for (int kk = 0; kk < 4; ++kk) {
            bf16x8 aq[2], bk[2];
#pragma unroll
            for (int i = 0; i < 2; ++i)
                aq[i] = *(const bf16x8*)&Qs[(wm * 32 + i * 16 + l15) * HD + kk * 32 + quad * 8];
#pragma unroll
            for (int j = 0; j < 2; ++j)
                bk[j] = *(const bf16x8*)&Ks[(wn * 32 + j * 16 + l15) * HD + kk * 32 + quad * 8];
#pragma unroll
            for (int i = 0; i < 2; ++i)
#pragma unroll
                for (int j = 0; j < 2; ++j)
                    sacc[i][j] = __builtin_amdgcn_mfma_f32_16x16x32_bf16(aq[i], bk[j], sacc[i][j], 0, 0, 0);
        }

        // scale + inverted mask + per-row max (this wave's 32-col half)
        float rmax[2][4];
#pragma unroll
        for (int i = 0; i < 2; ++i)
#pragma unroll
            for (int r = 0; r < 4; ++r) rmax[i][r] = -3.0e38f;
#pragma unroll
        for (int i = 0; i < 2; ++i)
#pragma unroll
            for (int j = 0; j < 2; ++j)
#pragma unroll
                for (int r = 0; r < 4; ++r) {
                    const int row = wm * 32 + i * 16 + quad * 4 + r;
                    const int col = wn * 32 + j * 16 + l15;
                    const int qq = q0 + row, kk2 = k0 + col;
                    float v = sacc[i][j][r] * SM_SCALE;
                    if (!((kk2 > qq) || (kk2 <= qq - 1024))) v = -1e30f;
                    sacc[i][j][r] = v;
                    rmax[i][r] = fmaxf(rmax[i][r], v);
                }
#pragma unroll
        for (int d = 1; d < 16; d <<= 1)
#pragma unroll
            for (int i = 0; i < 2; ++i)
#pragma unroll
                for (int r = 0; r < 4; ++r)
                    rmax[i][r] = fmaxf(rmax[i][r], __shfl_xor(rmax[i][r], d, 64));
        if (l15 == 0)
#pragma unroll
            for (int i = 0; i < 2; ++i)
#pragma unroll
                for (int r = 0; r < 4; ++r)
                    wmaxs[wn * 64 + wm * 32 + i * 16 + quad * 4 + r] = rmax[i][r];
        __syncthreads();   // b2: row maxima visible

        float mnew[2][4], alpha[2][4], rsum[2][4];
#pragma unroll
        for (int i = 0; i < 2; ++i)
#pragma unroll
            for (int r = 0; r < 4; ++r) {
                const int row = wm * 32 + i * 16 + quad * 4 + r;
                const float mo = mst[row];
                const float mn = fmaxf(mo, fmaxf(wmaxs[row], wmaxs[64 + row]));
                mnew[i][r] = mn;
                alpha[i][r] = __expf(mo - mn);
                rsum[i][r] = 0.f;
            }
#pragma unroll
        for (int i = 0; i < 2; ++i)
#pragma unroll
            for (int j = 0; j < 2; ++j)
#pragma unroll
                for (int r = 0; r < 4; ++r) {
                    const int row = wm * 32 + i * 16 + quad * 4 + r;
                    const int col = wn * 32 + j * 16 + l15;
                    const float p = __expf(sacc[i][j][r] - mnew[i][r]);
                    rsum[i][r] += p;
                    Ps[row * 64 + col] = (bf16)p;
                }
#pragma unroll
        for (int d = 1; d < 16; d <<= 1)
#pragma unroll
            for (int i = 0; i < 2; ++i)
#pragma unroll
                for (int r = 0; r < 4; ++r)
                    rsum[i][r] += __shfl_xor(rsum[i][r], d, 64);
        if (l15 == 0)
#pragma unroll
            for (int i = 0; i < 2; ++i)
#pragma unroll
                for (int r = 0; r < 4; ++r)
                    wsums[wn * 64 + wm * 32 + i * 16 + quad * 4 + r] = rsum[i][r];
        __syncthreads();   // b3: P + partial sums visible

        if (wn == 0 && l15 == 0)
#pragma unroll
            for (int i = 0; i < 2; ++i)
#pragma unroll
                for (int r = 0; r < 4; ++r) {
                    const int row = wm * 32 + i * 16 + quad * 4 + r;
                    lst[row] = lst[row] * alpha[i][r] + wsums[row] + wsums[64 + row];
                    mst[row] = mnew[i][r];
                }
        // rescale O and accumulate P.V  (wave computes 32 rows x 64 hd)
#pragma unroll
        for (int i = 0; i < 2; ++i)
#pragma unroll
            for (int j = 0; j < 4; ++j)
#pragma unroll
                for (int r = 0; r < 4; ++r) oacc[i][j][r] *= alpha[i][r];
#pragma unroll
        for (int ks = 0; ks < 2; ++ks) {
            bf16x8 pa[2], vb[4];
#pragma unroll
            for (int i = 0; i < 2; ++i)
                pa[i] = *(const bf16x8*)&Ps[(wm * 32 + i * 16 + l15) * 64 + ks * 32 + quad * 8];
#pragma unroll
            for (int j = 0; j < 4; ++j)
                vb[j] = *(const bf16x8*)&Vts[(wn * 64 + j * 16 + l15) * 64 + ks * 32 + quad * 8];
#pragma unroll
            for (int i = 0; i < 2; ++i)
#pragma unroll
                for (int j = 0; j < 4; ++j)
                    oacc[i][j] = __builtin_amdgcn_mfma_f32_16x16x32_bf16(pa[i], vb[j], oacc[i][j], 0, 0, 0);
        }
        __syncthreads();   // b4: protect LDS + state for next tile
    }

    // epilogue: O /= l, write bf16 to attn buffer [L][2048]
#pragma unroll
    for (int i = 0; i < 2; ++i)
#pragma unroll
        for (int r = 0; r < 4; ++r) {
            const int row = wm * 32 + i * 16 + quad * 4 + r;
            const float inv = 1.0f / lst[row];
#pragma unroll
            for (int j = 0; j < 4; ++j)
                Ob[(long)(q0 + row) * D_MODEL + hq * HD + wn * 64 + j * 16 + l15] =
                    (bf16)(oacc[i][j][r] * inv);
        }
}

// ---------------------------------------------------------------------------
extern "C" void kernel_launch(void* const* d_in, const int* in_sizes, int n_in,
                              void* d_out, int out_size, void* d_ws, size_t ws_size,
                              hipStream_t stream) {
    (void)in_sizes; (void)n_in; (void)out_size; (void)ws_size;
    const float* x    = (const float*)d_in[0];
    const float* Wqkv = (const float*)d_in[1];
    const float* Wo   = (const float*)d_in[2];
    const float* s    = (const float*)d_in[3];
    float* out = (float*)d_out;

    char* ws = (char*)d_ws;
    bf16* xb    = (bf16*)ws;  ws += (size_t)D_MODEL * D_MODEL * 2;       // 8 MB
    bf16* wqkvT = (bf16*)ws;  ws += (size_t)QKV_N * D_MODEL * 2;         // 12.6 MB
    bf16* woT   = (bf16*)ws;  ws += (size_t)D_MODEL * D_MODEL * 2;       // 8 MB
    bf16* Qb    = (bf16*)ws;  ws += (size_t)16 * L_SEQ * HD * 2;         // 8 MB
    bf16* Kb    = (bf16*)ws;  ws += (size_t)4 * L_SEQ * HD * 2;          // 2 MB
    bf16* Vtb   = (bf16*)ws;  ws += (size_t)4 * HD * L_SEQ * 2;          // 2 MB
    bf16* attnb = (bf16*)ws;  ws += (size_t)L_SEQ * D_MODEL * 2;         // 8 MB
    float* proj = (float*)ws; ws += (size_t)L_SEQ * QKV_N * 4;           // 25.2 MB

    cast_f32_bf16<<<(D_MODEL * D_MODEL) / 1024, 256, 0, stream>>>(x, xb, D_MODEL * D_MODEL);
    transpose_cast<<<dim3(QKV_N / 32, D_MODEL / 32, 1), dim3(32, 8), 0, stream>>>(
        Wqkv, QKV_N, wqkvT, D_MODEL, 0, 0);
    transpose_cast<<<dim3(D_MODEL / 32, D_MODEL / 32, 1), dim3(32, 8), 0, stream>>>(
        Wo, D_MODEL, woT, D_MODEL, 0, 0);

    gemm_bt<<<dim3(QKV_N / 128, L_SEQ / 128), 256, 0, stream>>>(
        xb, wqkvT, proj, L_SEQ, QKV_N, D_MODEL);

    rope_split<<<(L_SEQ * 20 * 64) / 256, 256, 0, stream>>>(proj, Qb, Kb);
    // V^T per kv-head: dst[h][d][l] = proj[l][2560 + h*128 + d]
    transpose_cast<<<dim3(HD / 32, L_SEQ / 32, 4), dim3(32, 8), 0, stream>>>(
        proj + 2560, QKV_N, Vtb, L_SEQ, 128, (long)HD * L_SEQ);

    attn_kernel<<<dim3(L_SEQ / 64, 16), 256, 0, stream>>>(Qb, Kb, Vtb, s, attnb);

    gemm_bt<<<dim3(D_MODEL / 128, L_SEQ / 128), 256, 0, stream>>>(
        attnb, woT, out, L_SEQ, D_MODEL, D_MODEL);
}

// Round 2
// 294.724 us; speedup vs baseline: 1.3378x; 1.3378x over previous
//
#include <hip/hip_runtime.h>
#include <hip/hip_bf16.h>
#include <math.h>

typedef __bf16 bf16;
typedef __bf16 bf16x8 __attribute__((ext_vector_type(8)));
typedef __bf16 bf16x4v __attribute__((ext_vector_type(4)));
typedef float f32x4 __attribute__((ext_vector_type(4)));

#define GLD16(gp, lp) __builtin_amdgcn_global_load_lds( \
    (__attribute__((address_space(1))) void*)(void*)(gp), \
    (__attribute__((address_space(3))) void*)(lp), 16, 0, 0)

#define L_SEQ 2048
#define D_MODEL 2048
#define QKV_N 3072
#define HD 128
#define SM_SCALE 0.08838834764831843f   // 1/sqrt(128)

// ---------------------------------------------------------------------------
// elementwise fp32 -> bf16 cast (4 elems/thread)
// ---------------------------------------------------------------------------
__global__ __launch_bounds__(256) void cast_f32_bf16(const float* __restrict__ src,
                                                     bf16* __restrict__ dst, int n) {
    int i = blockIdx.x * 256 + threadIdx.x;
    int idx = i * 4;
    if (idx >= n) return;
    float4 f = *(const float4*)(src + idx);
    bf16x4v o;
    o.x = (bf16)f.x; o.y = (bf16)f.y; o.z = (bf16)f.z; o.w = (bf16)f.w;
    *(bf16x4v*)(dst + idx) = o;
}

// ---------------------------------------------------------------------------
// tiled transpose-cast: dst[c][r] = (bf16) src[r][c].  32x32 tiles.
// ---------------------------------------------------------------------------
__global__ __launch_bounds__(256) void transpose_cast(const float* __restrict__ src, long ld_src,
                                                      bf16* __restrict__ dst, long ld_dst,
                                                      long zsrc, long zdst) {
    __shared__ float tile[32][33];
    src += (long)blockIdx.z * zsrc;
    dst += (long)blockIdx.z * zdst;
    int tx = threadIdx.x, ty = threadIdx.y;
    long c  = blockIdx.x * 32 + tx;
    long r0 = blockIdx.y * 32;
#pragma unroll
    for (int i = 0; i < 4; ++i)
        tile[ty + i * 8][tx] = src[(r0 + ty + i * 8) * ld_src + c];
    __syncthreads();
    long c0 = blockIdx.x * 32;
#pragma unroll
    for (int i = 0; i < 4; ++i)
        dst[(c0 + ty + i * 8) * ld_dst + r0 + tx] = (bf16)tile[tx][ty + i * 8];
}

// ---------------------------------------------------------------------------
// GEMM: C[M][N] fp32 = A[M][K] bf16 x Bt[N][K] bf16.  128x128 tile, 4 waves,
// 16x16x32 MFMA, BK=32.  LDS blocks XOR-swizzled: block' = block ^ ((row>>1)&3)
// -> fragment ds_read_b128 is 2-way (free) instead of 8-way.
// ---------------------------------------------------------------------------
__global__ __launch_bounds__(256) void gemm_bt(const bf16* __restrict__ A,
                                               const bf16* __restrict__ Bt,
                                               float* __restrict__ C,
                                               int M, int N, int K) {
    __shared__ __align__(16) bf16 As[128 * 32];
    __shared__ __align__(16) bf16 Bs[128 * 32];
    const int tid = threadIdx.x;
    const int wid = tid >> 6, lane = tid & 63;
    const int quad = lane >> 4, l15 = lane & 15;
    const int wm = wid & 1, wn = wid >> 1;
    const long m0 = (long)blockIdx.y * 128, n0 = (long)blockIdx.x * 128;

    const int srow = wid * 32 + (lane >> 2);                    // staging row
    const int scol = ((lane & 3) ^ ((lane >> 3) & 3)) * 8;      // swizzled col

    f32x4 acc[4][4];
#pragma unroll
    for (int i = 0; i < 4; ++i)
#pragma unroll
        for (int j = 0; j < 4; ++j) acc[i][j] = (f32x4){0.f, 0.f, 0.f, 0.f};

    const bf16* Ap  = A  + (m0 + srow) * K + scol;
    const bf16* Ap2 = Ap + (long)16 * K;
    const bf16* Bp  = Bt + (n0 + srow) * K + scol;
    const bf16* Bp2 = Bp + (long)16 * K;
    bf16* lA  = &As[(wid * 32) * 32];
    bf16* lA2 = &As[(wid * 32 + 16) * 32];
    bf16* lB  = &Bs[(wid * 32) * 32];
    bf16* lB2 = &Bs[(wid * 32 + 16) * 32];

    const int rsw = ((l15 >> 1) & 3);   // read-side swizzle

    for (int k0 = 0; k0 < K; k0 += 32) {
        GLD16(Ap + k0, lA);
        GLD16(Ap2 + k0, lA2);
        GLD16(Bp + k0, lB);
        GLD16(Bp2 + k0, lB2);
        __syncthreads();
        bf16x8 af[4], bfr[4];
#pragma unroll
        for (int i = 0; i < 4; ++i)
            af[i] = *(const bf16x8*)&As[(wm * 64 + i * 16 + l15) * 32 + (quad ^ rsw) * 8];
#pragma unroll
        for (int j = 0; j < 4; ++j)
            bfr[j] = *(const bf16x8*)&Bs[(wn * 64 + j * 16 + l15) * 32 + (quad ^ rsw) * 8];
#pragma unroll
        for (int i = 0; i < 4; ++i)
#pragma unroll
            for (int j = 0; j < 4; ++j)
                acc[i][j] = __builtin_amdgcn_mfma_f32_16x16x32_bf16(af[i], bfr[j], acc[i][j], 0, 0, 0);
        __syncthreads();
    }
#pragma unroll
    for (int i = 0; i < 4; ++i)
#pragma unroll
        for (int j = 0; j < 4; ++j) {
            long m = m0 + wm * 64 + i * 16 + quad * 4;
            long n = n0 + wn * 64 + j * 16 + l15;
#pragma unroll
            for (int r = 0; r < 4; ++r)
                C[(m + r) * (long)N + n] = acc[i][j][r];
        }
}

// ---------------------------------------------------------------------------
// RoPE (half-truncate) + split of proj into Q [16][L][128] and K [4][L][128].
// ---------------------------------------------------------------------------
__global__ __launch_bounds__(256) void rope_split(const float* __restrict__ proj,
                                                  bf16* __restrict__ Qb,
                                                  bf16* __restrict__ Kb) {
    const int idx = blockIdx.x * 256 + threadIdx.x;   // L*20*64 total, exact
    const int d = idx & 63;
    const int head = (idx >> 6) % 20;
    const int l = idx / (64 * 20);
    const long basecol = head < 16 ? (long)head * 128 : 2048L + (long)(head - 16) * 128;
    const float x1 = proj[(long)l * QKV_N + basecol + d];
    const float x2 = proj[(long)l * QKV_N + basecol + d + 64];
    float o1, o2;
    if (d < 32) {
        const float t = (float)d / 31.0f;
        const float freq = powf(1.0f / 1024.0f, t);
        const float th = (float)l * freq;
        const float c = cosf(th), s = sinf(th);
        o1 = x1 * c + x2 * s;
        o2 = x2 * c - x1 * s;
    } else {  // zero freqs -> identity
        o1 = x1; o2 = x2;
    }
    bf16* dst = head < 16 ? Qb + (long)head * L_SEQ * HD : Kb + (long)(head - 16) * L_SEQ * HD;
    dst[(long)l * HD + d] = (bf16)o1;
    dst[(long)l * HD + d + 64] = (bf16)o2;
}

// ---------------------------------------------------------------------------
// Flash-style GQA attention, inverted mask: valid(q,k) = (k>q) || (k<=q-1024).
// One wave owns 16 q-rows: row stats in registers (no stat LDS, 2 barriers /
// k-tile).  All staged tiles XOR-swizzled (block' = block ^ (row&7)) so every
// fragment ds_read_b128 is 2-way (free).  P: per-wave LDS region, same-wave
// write->read (DS pipe in-order), padded stride 68.
// Block remap: heavy q-tiles (qt<16, 17..32 k-tiles) dispatch first.
// ---------------------------------------------------------------------------
__global__ __launch_bounds__(256) void attn_kernel(const bf16* __restrict__ Qb,
                                                   const bf16* __restrict__ Kb,
                                                   const bf16* __restrict__ Vtb,
                                                   const float* __restrict__ sink,
                                                   bf16* __restrict__ Ob) {
    __shared__ __align__(16) bf16 Qs[64 * 128];
    __shared__ __align__(16) bf16 Ks[64 * 128];
    __shared__ __align__(16) bf16 Vts[128 * 64];   // [hd][kseq]
    __shared__ __align__(16) bf16 Ps[4 * 16 * 68]; // per-wave 16x64, pad->68

    const int bid = blockIdx.x;
    const int u = bid & 15;
    const int hq = (bid >> 4) & 15;
    const int qt = (bid < 256) ? u : 16 + u;
    const int h = hq >> 2;
    const int q0 = qt * 64;
    const int tid = threadIdx.x;
    const int wid = tid >> 6, lane = tid & 63;
    const int quad = lane >> 4, l15 = lane & 15;

    const bf16* Qg = Qb + (long)hq * L_SEQ * HD;
    const bf16* Kg = Kb + (long)h * L_SEQ * HD;
    const bf16* Vg = Vtb + (long)h * HD * L_SEQ;

    // stage Q tile (64x128, swizzled)
#pragma unroll
    for (int i = 0; i < 4; ++i) {
        int row = wid * 16 + i * 4 + quad;
        int g = l15 ^ (row & 7);
        GLD16(Qg + (long)(q0 + row) * HD + g * 8, &Qs[(wid * 16 + i * 4) * 128]);
    }

    float m_r[4], l_r[4];
    const float sv = sink[hq];
#pragma unroll
    for (int r = 0; r < 4; ++r) { m_r[r] = sv; l_r[r] = 1.0f; }

    f32x4 oacc[8];
#pragma unroll
    for (int j = 0; j < 8; ++j) oacc[j] = (f32x4){0.f, 0.f, 0.f, 0.f};

    const int qrow = q0 + wid * 16 + quad * 4;   // +r = this lane's q rows

    for (int kt = 0; kt < 32; ++kt) {
        if (kt < qt && kt > qt - 16) continue;   // fully-masked band
        const int k0 = kt * 64;
        __syncthreads();   // all waves done reading previous K/V
#pragma unroll
        for (int i = 0; i < 4; ++i) {
            int row = wid * 16 + i * 4 + quad;
            int g = l15 ^ (row & 7);
            GLD16(Kg + (long)(k0 + row) * HD + g * 8, &Ks[(wid * 16 + i * 4) * 128]);
        }
#pragma unroll
        for (int i = 0; i < 4; ++i) {
            int row = wid * 32 + i * 8 + (lane >> 3);
            int g = (lane & 7) ^ ((lane >> 3) & 7);
            GLD16(Vg + (long)row * L_SEQ + k0 + g * 8, &Vts[(wid * 32 + i * 8) * 64]);
        }
        __syncthreads();   // staged (barrier drains vmcnt)

        // S = Q K^T : wave computes 16x64
        f32x4 sacc[4];
#pragma unroll
        for (int j = 0; j < 4; ++j) sacc[j] = (f32x4){0.f, 0.f, 0.f, 0.f};
        bf16x8 aq[4];
#pragma unroll
        for (int kk = 0; kk < 4; ++kk)
            aq[kk] = *(const bf16x8*)&Qs[(wid * 16 + l15) * 128 + ((kk * 4 + quad) ^ (l15 & 7)) * 8];
#pragma unroll
        for (int j = 0; j < 4; ++j)
#pragma unroll
            for (int kk = 0; kk < 4; ++kk) {
                bf16x8 bk = *(const bf16x8*)&Ks[(j * 16 + l15) * 128 + ((kk * 4 + quad) ^ (l15 & 7)) * 8];
                sacc[j] = __builtin_amdgcn_mfma_f32_16x16x32_bf16(aq[kk], bk, sacc[j], 0, 0, 0);
            }

        // scale + inverted mask + register row stats
        float rmax[4];
#pragma unroll
        for (int r = 0; r < 4; ++r) rmax[r] = -3.0e38f;
#pragma unroll
        for (int j = 0; j < 4; ++j)
#pragma unroll
            for (int r = 0; r < 4; ++r) {
                const int qq = qrow + r, kk2 = k0 + j * 16 + l15;
                float v = sacc[j][r] * SM_SCALE;
                if (!((kk2 > qq) || (kk2 <= qq - 1024))) v = -1e30f;
                sacc[j][r] = v;
                rmax[r] = fmaxf(rmax[r], v);
            }
#pragma unroll
        for (int d = 1; d < 16; d <<= 1)
#pragma unroll
            for (int r = 0; r < 4; ++r)
                rmax[r] = fmaxf(rmax[r], __shfl_xor(rmax[r], d, 64));
        float alpha[4], rsum[4];
#pragma unroll
        for (int r = 0; r < 4; ++r) {
            const float mn = fmaxf(m_r[r], rmax[r]);
            alpha[r] = __expf(m_r[r] - mn);
            m_r[r] = mn;
            rsum[r] = 0.f;
        }
#pragma unroll
        for (int j = 0; j < 4; ++j)
#pragma unroll
            for (int r = 0; r < 4; ++r) {
                const float p = __expf(sacc[j][r] - m_r[r]);
                rsum[r] += p;
                Ps[wid * 1088 + (quad * 4 + r) * 68 + j * 16 + l15] = (bf16)p;
            }
#pragma unroll
        for (int d = 1; d < 16; d <<= 1)
#pragma unroll
            for (int r = 0; r < 4; ++r)
                rsum[r] += __shfl_xor(rsum[r], d, 64);
#pragma unroll
        for (int r = 0; r < 4; ++r)
            l_r[r] = l_r[r] * alpha[r] + rsum[r];
#pragma unroll
        for (int j = 0; j < 8; ++j)
#pragma unroll
            for (int r = 0; r < 4; ++r) oacc[j][r] *= alpha[r];

        __builtin_amdgcn_wave_barrier();   // pin P ds_write before ds_read

        // O += P V : wave computes 16x128
        bf16x8 pa[2];
#pragma unroll
        for (int ks = 0; ks < 2; ++ks)
            pa[ks] = *(const bf16x8*)&Ps[wid * 1088 + l15 * 68 + ks * 32 + quad * 8];
#pragma unroll
        for (int j = 0; j < 8; ++j)
#pragma unroll
            for (int ks = 0; ks < 2; ++ks) {
                bf16x8 vb = *(const bf16x8*)&Vts[(j * 16 + l15) * 64 + ((ks * 4 + quad) ^ (l15 & 7)) * 8];
                oacc[j] = __builtin_amdgcn_mfma_f32_16x16x32_bf16(pa[ks], vb, oacc[j], 0, 0, 0);
            }
    }

    // epilogue: O /= l, write bf16 to attn buffer [L][2048]
#pragma unroll
    for (int r = 0; r < 4; ++r) {
        const float inv = 1.0f / l_r[r];
#pragma unroll
        for (int j = 0; j < 8; ++j)
            Ob[(long)(qrow + r) * D_MODEL + hq * HD + j * 16 + l15] =
                (bf16)(oacc[j][r] * inv);
    }
}

// ---------------------------------------------------------------------------
extern "C" void kernel_launch(void* const* d_in, const int* in_sizes, int n_in,
                              void* d_out, int out_size, void* d_ws, size_t ws_size,
                              hipStream_t stream) {
    (void)in_sizes; (void)n_in; (void)out_size; (void)ws_size;
    const float* x    = (const float*)d_in[0];
    const float* Wqkv = (const float*)d_in[1];
    const float* Wo   = (const float*)d_in[2];
    const float* s    = (const float*)d_in[3];
    float* out = (float*)d_out;

    char* ws = (char*)d_ws;
    bf16* xb    = (bf16*)ws;  ws += (size_t)D_MODEL * D_MODEL * 2;
    bf16* wqkvT = (bf16*)ws;  ws += (size_t)QKV_N * D_MODEL * 2;
    bf16* woT   = (bf16*)ws;  ws += (size_t)D_MODEL * D_MODEL * 2;
    bf16* Qb    = (bf16*)ws;  ws += (size_t)16 * L_SEQ * HD * 2;
    bf16* Kb    = (bf16*)ws;  ws += (size_t)4 * L_SEQ * HD * 2;
    bf16* Vtb   = (bf16*)ws;  ws += (size_t)4 * HD * L_SEQ * 2;
    bf16* attnb = (bf16*)ws;  ws += (size_t)L_SEQ * D_MODEL * 2;
    float* proj = (float*)ws; ws += (size_t)L_SEQ * QKV_N * 4;

    cast_f32_bf16<<<(D_MODEL * D_MODEL) / 1024, 256, 0, stream>>>(x, xb, D_MODEL * D_MODEL);
    transpose_cast<<<dim3(QKV_N / 32, D_MODEL / 32, 1), dim3(32, 8), 0, stream>>>(
        Wqkv, QKV_N, wqkvT, D_MODEL, 0, 0);
    transpose_cast<<<dim3(D_MODEL / 32, D_MODEL / 32, 1), dim3(32, 8), 0, stream>>>(
        Wo, D_MODEL, woT, D_MODEL, 0, 0);

    gemm_bt<<<dim3(QKV_N / 128, L_SEQ / 128), 256, 0, stream>>>(
        xb, wqkvT, proj, L_SEQ, QKV_N, D_MODEL);

    rope_split<<<(L_SEQ * 20 * 64) / 256, 256, 0, stream>>>(proj, Qb, Kb);
    transpose_cast<<<dim3(HD / 32, L_SEQ / 32, 4), dim3(32, 8), 0, stream>>>(
        proj + 2560, QKV_N, Vtb, L_SEQ, 128, (long)HD * L_SEQ);

    attn_kernel<<<512, 256, 0, stream>>>(Qb, Kb, Vtb, s, attnb);

    gemm_bt<<<dim3(D_MODEL / 128, L_SEQ / 128), 256, 0, stream>>>(
        attnb, woT, out, L_SEQ, D_MODEL, D_MODEL);
}

// Round 3
// 291.402 us; speedup vs baseline: 1.3531x; 1.0114x over previous
//
#include <hip/hip_runtime.h>
#include <hip/hip_bf16.h>
#include <math.h>

typedef __bf16 bf16;
typedef __bf16 bf16x8 __attribute__((ext_vector_type(8)));
typedef __bf16 bf16x4v __attribute__((ext_vector_type(4)));
typedef float f32x4 __attribute__((ext_vector_type(4)));

#define GLD16(gp, lp) __builtin_amdgcn_global_load_lds( \
    (__attribute__((address_space(1))) void*)(void*)(gp), \
    (__attribute__((address_space(3))) void*)(lp), 16, 0, 0)

#define L_SEQ 2048
#define D_MODEL 2048
#define QKV_N 3072
#define HD 128
#define SM_SCALE 0.08838834764831843f            // 1/sqrt(128)
#define QSCALE 0.1275310242959836f               // SM_SCALE * log2(e)
#define LOG2E 1.4426950408889634f

// ---------------------------------------------------------------------------
// elementwise fp32 -> bf16 cast (4 elems/thread)
// ---------------------------------------------------------------------------
__global__ __launch_bounds__(256) void cast_f32_bf16(const float* __restrict__ src,
                                                     bf16* __restrict__ dst, int n) {
    int i = blockIdx.x * 256 + threadIdx.x;
    int idx = i * 4;
    if (idx >= n) return;
    float4 f = *(const float4*)(src + idx);
    bf16x4v o;
    o.x = (bf16)f.x; o.y = (bf16)f.y; o.z = (bf16)f.z; o.w = (bf16)f.w;
    *(bf16x4v*)(dst + idx) = o;
}

// ---------------------------------------------------------------------------
// tiled transpose-cast: dst[c][r] = (bf16) src[r][c].  32x32 tiles.
// ---------------------------------------------------------------------------
__global__ __launch_bounds__(256) void transpose_cast(const float* __restrict__ src, long ld_src,
                                                      bf16* __restrict__ dst, long ld_dst,
                                                      long zsrc, long zdst) {
    __shared__ float tile[32][33];
    src += (long)blockIdx.z * zsrc;
    dst += (long)blockIdx.z * zdst;
    int tx = threadIdx.x, ty = threadIdx.y;
    long c  = blockIdx.x * 32 + tx;
    long r0 = blockIdx.y * 32;
#pragma unroll
    for (int i = 0; i < 4; ++i)
        tile[ty + i * 8][tx] = src[(r0 + ty + i * 8) * ld_src + c];
    __syncthreads();
    long c0 = blockIdx.x * 32;
#pragma unroll
    for (int i = 0; i < 4; ++i)
        dst[(c0 + ty + i * 8) * ld_dst + r0 + tx] = (bf16)tile[tx][ty + i * 8];
}

// ---------------------------------------------------------------------------
// GEMM: C[M][N] fp32 = A[M][K] bf16 x Bt[N][K] bf16.  128x128 tile, 4 waves,
// 16x16x32 MFMA, BK=32, XOR-swizzled LDS (2-way fragment reads).
// ---------------------------------------------------------------------------
__global__ __launch_bounds__(256) void gemm_bt(const bf16* __restrict__ A,
                                               const bf16* __restrict__ Bt,
                                               float* __restrict__ C,
                                               int M, int N, int K) {
    __shared__ __align__(16) bf16 As[128 * 32];
    __shared__ __align__(16) bf16 Bs[128 * 32];
    const int tid = threadIdx.x;
    const int wid = tid >> 6, lane = tid & 63;
    const int quad = lane >> 4, l15 = lane & 15;
    const int wm = wid & 1, wn = wid >> 1;
    const long m0 = (long)blockIdx.y * 128, n0 = (long)blockIdx.x * 128;

    const int srow = wid * 32 + (lane >> 2);
    const int scol = ((lane & 3) ^ ((lane >> 3) & 3)) * 8;

    f32x4 acc[4][4];
#pragma unroll
    for (int i = 0; i < 4; ++i)
#pragma unroll
        for (int j = 0; j < 4; ++j) acc[i][j] = (f32x4){0.f, 0.f, 0.f, 0.f};

    const bf16* Ap  = A  + (m0 + srow) * K + scol;
    const bf16* Ap2 = Ap + (long)16 * K;
    const bf16* Bp  = Bt + (n0 + srow) * K + scol;
    const bf16* Bp2 = Bp + (long)16 * K;
    bf16* lA  = &As[(wid * 32) * 32];
    bf16* lA2 = &As[(wid * 32 + 16) * 32];
    bf16* lB  = &Bs[(wid * 32) * 32];
    bf16* lB2 = &Bs[(wid * 32 + 16) * 32];

    const int rsw = ((l15 >> 1) & 3);

    for (int k0 = 0; k0 < K; k0 += 32) {
        GLD16(Ap + k0, lA);
        GLD16(Ap2 + k0, lA2);
        GLD16(Bp + k0, lB);
        GLD16(Bp2 + k0, lB2);
        __syncthreads();
        bf16x8 af[4], bfr[4];
#pragma unroll
        for (int i = 0; i < 4; ++i)
            af[i] = *(const bf16x8*)&As[(wm * 64 + i * 16 + l15) * 32 + (quad ^ rsw) * 8];
#pragma unroll
        for (int j = 0; j < 4; ++j)
            bfr[j] = *(const bf16x8*)&Bs[(wn * 64 + j * 16 + l15) * 32 + (quad ^ rsw) * 8];
#pragma unroll
        for (int i = 0; i < 4; ++i)
#pragma unroll
            for (int j = 0; j < 4; ++j)
                acc[i][j] = __builtin_amdgcn_mfma_f32_16x16x32_bf16(af[i], bfr[j], acc[i][j], 0, 0, 0);
        __syncthreads();
    }
#pragma unroll
    for (int i = 0; i < 4; ++i)
#pragma unroll
        for (int j = 0; j < 4; ++j) {
            long m = m0 + wm * 64 + i * 16 + quad * 4;
            long n = n0 + wn * 64 + j * 16 + l15;
#pragma unroll
            for (int r = 0; r < 4; ++r)
                C[(m + r) * (long)N + n] = acc[i][j][r];
        }
}

// ---------------------------------------------------------------------------
// RoPE (half-truncate) + split into Q [16][L][128] (pre-scaled by
// SM_SCALE*log2e for exp2-domain softmax) and K [4][L][128].
// ---------------------------------------------------------------------------
__global__ __launch_bounds__(256) void rope_split(const float* __restrict__ proj,
                                                  bf16* __restrict__ Qb,
                                                  bf16* __restrict__ Kb) {
    const int idx = blockIdx.x * 256 + threadIdx.x;   // L*20*64 total, exact
    const int d = idx & 63;
    const int head = (idx >> 6) % 20;
    const int l = idx / (64 * 20);
    const long basecol = head < 16 ? (long)head * 128 : 2048L + (long)(head - 16) * 128;
    const float x1 = proj[(long)l * QKV_N + basecol + d];
    const float x2 = proj[(long)l * QKV_N + basecol + d + 64];
    float o1, o2;
    if (d < 32) {
        const float t = (float)d / 31.0f;
        const float freq = powf(1.0f / 1024.0f, t);
        const float th = (float)l * freq;
        const float c = cosf(th), s = sinf(th);
        o1 = x1 * c + x2 * s;
        o2 = x2 * c - x1 * s;
    } else {
        o1 = x1; o2 = x2;
    }
    const float sc = head < 16 ? QSCALE : 1.0f;
    bf16* dst = head < 16 ? Qb + (long)head * L_SEQ * HD : Kb + (long)(head - 16) * L_SEQ * HD;
    dst[(long)l * HD + d] = (bf16)(o1 * sc);
    dst[(long)l * HD + d + 64] = (bf16)(o2 * sc);
}

// ---------------------------------------------------------------------------
// Flash-style GQA attention, inverted mask: valid(q,k) = (k>q) || (k<=q-1024).
// 512 threads = 2 independent 4-wave groups splitting the valid k-tile list
// (interleaved), merged in-LDS at the end.  K-tile 32.  Q-frags in registers.
// exp2-domain softmax; row-sums via MFMA ones-column; mask only on the 4
// boundary k-tiles.  LDS 40 KB -> with grid 512 two blocks/CU = 16 waves/CU.
// ---------------------------------------------------------------------------
__global__ __launch_bounds__(512, 4) void attn_kernel(const bf16* __restrict__ Qb,
                                                      const bf16* __restrict__ Kb,
                                                      const bf16* __restrict__ Vtb,
                                                      const float* __restrict__ sink,
                                                      bf16* __restrict__ Ob) {
    __shared__ __align__(16) char smem[40960];

    const int bid = blockIdx.x;
    const int u = bid & 15;
    const int hq = (bid >> 4) & 15;
    const int qt = (bid < 256) ? u : 16 + u;       // heavy q-tiles first
    const int h = hq >> 2;
    const int q0 = qt * 64;
    const int tid = threadIdx.x;
    const int wid8 = tid >> 6;
    const int g = wid8 >> 2;                       // group 0/1
    const int w = wid8 & 3;                        // wave within group
    const int lane = tid & 63;
    const int quad = lane >> 4, l15 = lane & 15;

    bf16* Ks  = (bf16*)(smem + g * 20480);         // 32 x 128
    bf16* Vts = (bf16*)(smem + g * 20480 + 8192);  // 128 x 32
    bf16* Ps  = (bf16*)(smem + g * 20480 + 16384); // 4 waves x 16 x 32

    const bf16* Qg = Qb + (long)hq * L_SEQ * HD;
    const bf16* Kg = Kb + (long)h * L_SEQ * HD;
    const bf16* Vg = Vtb + (long)h * HD * L_SEQ;

    const int qrow16 = w * 16;                     // wave's rows in 64-row tile

    // Q fragments in registers (already scaled by SM_SCALE*log2e)
    bf16x8 aq[4];
#pragma unroll
    for (int kk = 0; kk < 4; ++kk)
        aq[kk] = *(const bf16x8*)(Qg + (long)(q0 + qrow16 + l15) * HD + kk * 32 + quad * 8);

    float m_r[4];
#pragma unroll
    for (int r = 0; r < 4; ++r) m_r[r] = -3.0e38f;
    f32x4 lsum = (f32x4){0.f, 0.f, 0.f, 0.f};
    f32x4 oacc[8];
#pragma unroll
    for (int j = 0; j < 8; ++j) oacc[j] = (f32x4){0.f, 0.f, 0.f, 0.f};

    const bf16 onev = (bf16)1.0f;
    const bf16x8 onesb = {onev, onev, onev, onev, onev, onev, onev, onev};

    // valid 32-col k-tiles: [0, 2qt-31] U [2qt, 63]
    const int lowcnt = (qt > 15) ? (2 * qt - 30) : 0;
    const int n = lowcnt + (64 - 2 * qt);
    const int iters = (n + 1) >> 1;

    for (int it = 0; it < iters; ++it) {
        const int i = 2 * it + g;
        const bool active = i < n;
        const int kt = (i < lowcnt) ? i : (2 * qt + (i - lowcnt));
        const int k0 = kt * 32;
        __syncthreads();   // group's waves done reading previous tiles
        if (active) {
#pragma unroll
            for (int ii = 0; ii < 2; ++ii) {       // K: 32 x 128
                int row = w * 8 + ii * 4 + quad;
                int gcol = (l15 ^ (row & 7)) * 8;
                GLD16(Kg + (long)(k0 + row) * HD + gcol, &Ks[(w * 8 + ii * 4) * 128]);
            }
#pragma unroll
            for (int ii = 0; ii < 2; ++ii) {       // V^T: 128 x 32
                int row = w * 32 + ii * 16 + (lane >> 2);
                int gcol = ((lane & 3) ^ ((lane >> 4) & 3)) * 8;
                GLD16(Vg + (long)row * L_SEQ + k0 + gcol, &Vts[(w * 32 + ii * 16) * 32]);
            }
        }
        __syncthreads();   // staged
        if (!active) continue;

        // S = Q K^T : wave computes 16 x 32
        f32x4 sacc[2];
        sacc[0] = (f32x4){0.f, 0.f, 0.f, 0.f};
        sacc[1] = (f32x4){0.f, 0.f, 0.f, 0.f};
#pragma unroll
        for (int j = 0; j < 2; ++j)
#pragma unroll
            for (int kk = 0; kk < 4; ++kk) {
                bf16x8 bk = *(const bf16x8*)&Ks[(j * 16 + l15) * 128 + ((kk * 4 + quad) ^ (l15 & 7)) * 8];
                sacc[j] = __builtin_amdgcn_mfma_f32_16x16x32_bf16(aq[kk], bk, sacc[j], 0, 0, 0);
            }

        // mask only boundary tiles (wave-uniform branch)
        if (kt == 2 * qt || kt == 2 * qt + 1 || kt == 2 * qt - 32 || kt == 2 * qt - 31) {
#pragma unroll
            for (int j = 0; j < 2; ++j)
#pragma unroll
                for (int r = 0; r < 4; ++r) {
                    const int qq = q0 + qrow16 + quad * 4 + r;
                    const int kk2 = k0 + j * 16 + l15;
                    if (!((kk2 > qq) || (kk2 <= qq - 1024))) sacc[j][r] = -1e30f;
                }
        }

        // row max (4-hop shuffle over 16 lanes)
        float rmax[4];
#pragma unroll
        for (int r = 0; r < 4; ++r) rmax[r] = fmaxf(sacc[0][r], sacc[1][r]);
#pragma unroll
        for (int d = 1; d < 16; d <<= 1)
#pragma unroll
            for (int r = 0; r < 4; ++r)
                rmax[r] = fmaxf(rmax[r], __shfl_xor(rmax[r], d, 64));
        float alpha[4];
#pragma unroll
        for (int r = 0; r < 4; ++r) {
            const float mn = fmaxf(m_r[r], rmax[r]);
            alpha[r] = exp2f(m_r[r] - mn);
            m_r[r] = mn;
        }
        // P = exp2(S - m) -> LDS (XOR-swizzled)
#pragma unroll
        for (int j = 0; j < 2; ++j)
#pragma unroll
            for (int r = 0; r < 4; ++r) {
                const float p = exp2f(sacc[j][r] - m_r[r]);
                const int blk = (j * 2 + (l15 >> 3)) ^ quad;
                Ps[w * 512 + (quad * 4 + r) * 32 + blk * 8 + (l15 & 7)] = (bf16)p;
            }
        // rescale O and l
#pragma unroll
        for (int j = 0; j < 8; ++j)
#pragma unroll
            for (int r = 0; r < 4; ++r) oacc[j][r] *= alpha[r];
#pragma unroll
        for (int r = 0; r < 4; ++r) lsum[r] *= alpha[r];

        __builtin_amdgcn_wave_barrier();   // pin P write before read (same wave)

        const bf16x8 pa = *(const bf16x8*)&Ps[w * 512 + l15 * 32 + ((quad ^ ((l15 >> 2) & 3)) * 8)];
        lsum = __builtin_amdgcn_mfma_f32_16x16x32_bf16(pa, onesb, lsum, 0, 0, 0);
#pragma unroll
        for (int j = 0; j < 8; ++j) {
            bf16x8 vb = *(const bf16x8*)&Vts[(j * 16 + l15) * 32 + ((quad ^ ((l15 >> 2) & 3)) * 8)];
            oacc[j] = __builtin_amdgcn_mfma_f32_16x16x32_bf16(pa, vb, oacc[j], 0, 0, 0);
        }
    }

    // ------------------- in-LDS merge of the two groups -------------------
    __syncthreads();
    float* O2 = (float*)smem;                 // 64 x 128 fp32 (32 KB)
    float* m2 = (float*)(smem + 32768);
    float* l2 = m2 + 64;
    if (g == 1) {
#pragma unroll
        for (int j = 0; j < 8; ++j)
#pragma unroll
            for (int r = 0; r < 4; ++r)
                O2[(qrow16 + quad * 4 + r) * 128 + j * 16 + l15] = oacc[j][r];
        if (l15 == 0)
#pragma unroll
            for (int r = 0; r < 4; ++r) {
                m2[qrow16 + quad * 4 + r] = m_r[r];
                l2[qrow16 + quad * 4 + r] = lsum[r];
            }
    }
    __syncthreads();
    if (g == 0) {
        const float sv2 = sink[hq] * LOG2E;
#pragma unroll
        for (int r = 0; r < 4; ++r) {
            const int row = qrow16 + quad * 4 + r;
            const float mA = m_r[r], mB = m2[row];
            const float mf = fmaxf(fmaxf(mA, mB), sv2);
            const float aA = exp2f(mA - mf), aB = exp2f(mB - mf);
            const float l = lsum[r] * aA + l2[row] * aB + exp2f(sv2 - mf);
            const float inv = 1.0f / l;
#pragma unroll
            for (int j = 0; j < 8; ++j)
                Ob[(long)(q0 + row) * D_MODEL + hq * HD + j * 16 + l15] =
                    (bf16)((oacc[j][r] * aA + O2[row * 128 + j * 16 + l15] * aB) * inv);
        }
    }
}

// ---------------------------------------------------------------------------
extern "C" void kernel_launch(void* const* d_in, const int* in_sizes, int n_in,
                              void* d_out, int out_size, void* d_ws, size_t ws_size,
                              hipStream_t stream) {
    (void)in_sizes; (void)n_in; (void)out_size; (void)ws_size;
    const float* x    = (const float*)d_in[0];
    const float* Wqkv = (const float*)d_in[1];
    const float* Wo   = (const float*)d_in[2];
    const float* s    = (const float*)d_in[3];
    float* out = (float*)d_out;

    char* ws = (char*)d_ws;
    bf16* xb    = (bf16*)ws;  ws += (size_t)D_MODEL * D_MODEL * 2;
    bf16* wqkvT = (bf16*)ws;  ws += (size_t)QKV_N * D_MODEL * 2;
    bf16* woT   = (bf16*)ws;  ws += (size_t)D_MODEL * D_MODEL * 2;
    bf16* Qb    = (bf16*)ws;  ws += (size_t)16 * L_SEQ * HD * 2;
    bf16* Kb    = (bf16*)ws;  ws += (size_t)4 * L_SEQ * HD * 2;
    bf16* Vtb   = (bf16*)ws;  ws += (size_t)4 * HD * L_SEQ * 2;
    bf16* attnb = (bf16*)ws;  ws += (size_t)L_SEQ * D_MODEL * 2;
    float* proj = (float*)ws; ws += (size_t)L_SEQ * QKV_N * 4;

    cast_f32_bf16<<<(D_MODEL * D_MODEL) / 1024, 256, 0, stream>>>(x, xb, D_MODEL * D_MODEL);
    transpose_cast<<<dim3(QKV_N / 32, D_MODEL / 32, 1), dim3(32, 8), 0, stream>>>(
        Wqkv, QKV_N, wqkvT, D_MODEL, 0, 0);
    transpose_cast<<<dim3(D_MODEL / 32, D_MODEL / 32, 1), dim3(32, 8), 0, stream>>>(
        Wo, D_MODEL, woT, D_MODEL, 0, 0);

    gemm_bt<<<dim3(QKV_N / 128, L_SEQ / 128), 256, 0, stream>>>(
        xb, wqkvT, proj, L_SEQ, QKV_N, D_MODEL);

    rope_split<<<(L_SEQ * 20 * 64) / 256, 256, 0, stream>>>(proj, Qb, Kb);
    transpose_cast<<<dim3(HD / 32, L_SEQ / 32, 4), dim3(32, 8), 0, stream>>>(
        proj + 2560, QKV_N, Vtb, L_SEQ, 128, (long)HD * L_SEQ);

    attn_kernel<<<512, 512, 0, stream>>>(Qb, Kb, Vtb, s, attnb);

    gemm_bt<<<dim3(D_MODEL / 128, L_SEQ / 128), 256, 0, stream>>>(
        attnb, woT, out, L_SEQ, D_MODEL, D_MODEL);
}

// Round 4
// 277.171 us; speedup vs baseline: 1.4225x; 1.0513x over previous
//
#include <hip/hip_runtime.h>
#include <hip/hip_bf16.h>
#include <math.h>

typedef __bf16 bf16;
typedef __bf16 bf16x8 __attribute__((ext_vector_type(8)));
typedef __bf16 bf16x4v __attribute__((ext_vector_type(4)));
typedef short s16x4 __attribute__((ext_vector_type(4)));
typedef float f32x4 __attribute__((ext_vector_type(4)));

#define GLD16(gp, lp) __builtin_amdgcn_global_load_lds( \
    (__attribute__((address_space(1))) void*)(void*)(gp), \
    (__attribute__((address_space(3))) void*)(lp), 16, 0, 0)

#define L_SEQ 2048
#define D_MODEL 2048
#define QKV_N 3072
#define HD 128
#define QSCALE 0.1275310242959836f               // (1/sqrt(128)) * log2(e)
#define LOG2E 1.4426950408889634f

// ---------------------------------------------------------------------------
// elementwise fp32 -> bf16 cast (4 elems/thread)
// ---------------------------------------------------------------------------
__global__ __launch_bounds__(256) void cast_f32_bf16(const float* __restrict__ src,
                                                     bf16* __restrict__ dst, int n) {
    int i = blockIdx.x * 256 + threadIdx.x;
    int idx = i * 4;
    if (idx >= n) return;
    float4 f = *(const float4*)(src + idx);
    bf16x4v o;
    o.x = (bf16)f.x; o.y = (bf16)f.y; o.z = (bf16)f.z; o.w = (bf16)f.w;
    *(bf16x4v*)(dst + idx) = o;
}

// ---------------------------------------------------------------------------
// tiled transpose-cast f32->bf16: dst[c][r] = (bf16) src[r][c].  32x32 tiles.
// ---------------------------------------------------------------------------
__global__ __launch_bounds__(256) void transpose_cast(const float* __restrict__ src, long ld_src,
                                                      bf16* __restrict__ dst, long ld_dst,
                                                      long zsrc, long zdst) {
    __shared__ float tile[32][33];
    src += (long)blockIdx.z * zsrc;
    dst += (long)blockIdx.z * zdst;
    int tx = threadIdx.x, ty = threadIdx.y;
    long c  = blockIdx.x * 32 + tx;
    long r0 = blockIdx.y * 32;
#pragma unroll
    for (int i = 0; i < 4; ++i)
        tile[ty + i * 8][tx] = src[(r0 + ty + i * 8) * ld_src + c];
    __syncthreads();
    long c0 = blockIdx.x * 32;
#pragma unroll
    for (int i = 0; i < 4; ++i)
        dst[(c0 + ty + i * 8) * ld_dst + r0 + tx] = (bf16)tile[tx][ty + i * 8];
}

// bf16 -> bf16 transpose (for V)
__global__ __launch_bounds__(256) void transpose_b(const bf16* __restrict__ src, long ld_src,
                                                   bf16* __restrict__ dst, long ld_dst,
                                                   long zsrc, long zdst) {
    __shared__ bf16 tile[32][34];
    src += (long)blockIdx.z * zsrc;
    dst += (long)blockIdx.z * zdst;
    int tx = threadIdx.x, ty = threadIdx.y;
    long c  = blockIdx.x * 32 + tx;
    long r0 = blockIdx.y * 32;
#pragma unroll
    for (int i = 0; i < 4; ++i)
        tile[ty + i * 8][tx] = src[(r0 + ty + i * 8) * ld_src + c];
    __syncthreads();
    long c0 = blockIdx.x * 32;
#pragma unroll
    for (int i = 0; i < 4; ++i)
        dst[(c0 + ty + i * 8) * ld_dst + r0 + tx] = tile[tx][ty + i * 8];
}

// ---------------------------------------------------------------------------
// GEMM: C[M][N] = A[M][K] bf16 x Bt[N][K] bf16.  128x128 tile, 4 waves,
// 16x16x32 MFMA, BK=32, XOR-swizzled LDS.  OT = float or bf16 output.
// ---------------------------------------------------------------------------
template <typename OT>
__global__ __launch_bounds__(256) void gemm_bt(const bf16* __restrict__ A,
                                               const bf16* __restrict__ Bt,
                                               OT* __restrict__ C,
                                               int M, int N, int K) {
    __shared__ __align__(16) bf16 As[128 * 32];
    __shared__ __align__(16) bf16 Bs[128 * 32];
    const int tid = threadIdx.x;
    const int wid = tid >> 6, lane = tid & 63;
    const int quad = lane >> 4, l15 = lane & 15;
    const int wm = wid & 1, wn = wid >> 1;
    const long m0 = (long)blockIdx.y * 128, n0 = (long)blockIdx.x * 128;

    const int srow = wid * 32 + (lane >> 2);
    const int scol = ((lane & 3) ^ ((lane >> 3) & 3)) * 8;

    f32x4 acc[4][4];
#pragma unroll
    for (int i = 0; i < 4; ++i)
#pragma unroll
        for (int j = 0; j < 4; ++j) acc[i][j] = (f32x4){0.f, 0.f, 0.f, 0.f};

    const bf16* Ap  = A  + (m0 + srow) * K + scol;
    const bf16* Ap2 = Ap + (long)16 * K;
    const bf16* Bp  = Bt + (n0 + srow) * K + scol;
    const bf16* Bp2 = Bp + (long)16 * K;
    bf16* lA  = &As[(wid * 32) * 32];
    bf16* lA2 = &As[(wid * 32 + 16) * 32];
    bf16* lB  = &Bs[(wid * 32) * 32];
    bf16* lB2 = &Bs[(wid * 32 + 16) * 32];

    const int rsw = ((l15 >> 1) & 3);

    for (int k0 = 0; k0 < K; k0 += 32) {
        GLD16(Ap + k0, lA);
        GLD16(Ap2 + k0, lA2);
        GLD16(Bp + k0, lB);
        GLD16(Bp2 + k0, lB2);
        __syncthreads();
        bf16x8 af[4], bfr[4];
#pragma unroll
        for (int i = 0; i < 4; ++i)
            af[i] = *(const bf16x8*)&As[(wm * 64 + i * 16 + l15) * 32 + (quad ^ rsw) * 8];
#pragma unroll
        for (int j = 0; j < 4; ++j)
            bfr[j] = *(const bf16x8*)&Bs[(wn * 64 + j * 16 + l15) * 32 + (quad ^ rsw) * 8];
#pragma unroll
        for (int i = 0; i < 4; ++i)
#pragma unroll
            for (int j = 0; j < 4; ++j)
                acc[i][j] = __builtin_amdgcn_mfma_f32_16x16x32_bf16(af[i], bfr[j], acc[i][j], 0, 0, 0);
        __syncthreads();
    }
#pragma unroll
    for (int i = 0; i < 4; ++i)
#pragma unroll
        for (int j = 0; j < 4; ++j) {
            long m = m0 + wm * 64 + i * 16 + quad * 4;
            long n = n0 + wn * 64 + j * 16 + l15;
#pragma unroll
            for (int r = 0; r < 4; ++r)
                C[(m + r) * (long)N + n] = (OT)acc[i][j][r];
        }
}

// ---------------------------------------------------------------------------
// RoPE (half-truncate) + split of bf16 proj into Q [16][L][128] (pre-scaled by
// SM_SCALE*log2e) and K [4][L][128].
// ---------------------------------------------------------------------------
__global__ __launch_bounds__(256) void rope_split(const bf16* __restrict__ proj,
                                                  bf16* __restrict__ Qb,
                                                  bf16* __restrict__ Kb) {
    const int idx = blockIdx.x * 256 + threadIdx.x;   // L*20*64 total, exact
    const int d = idx & 63;
    const int head = (idx >> 6) % 20;
    const int l = idx / (64 * 20);
    const long basecol = head < 16 ? (long)head * 128 : 2048L + (long)(head - 16) * 128;
    const float x1 = (float)proj[(long)l * QKV_N + basecol + d];
    const float x2 = (float)proj[(long)l * QKV_N + basecol + d + 64];
    float o1, o2;
    if (d < 32) {
        const float t = (float)d / 31.0f;
        const float freq = powf(1.0f / 1024.0f, t);
        const float th = (float)l * freq;
        const float c = cosf(th), s = sinf(th);
        o1 = x1 * c + x2 * s;
        o2 = x2 * c - x1 * s;
    } else {
        o1 = x1; o2 = x2;
    }
    const float sc = head < 16 ? QSCALE : 1.0f;
    bf16* dst = head < 16 ? Qb + (long)head * L_SEQ * HD : Kb + (long)(head - 16) * L_SEQ * HD;
    dst[(long)l * HD + d] = (bf16)(o1 * sc);
    dst[(long)l * HD + d + 64] = (bf16)(o2 * sc);
}

// ---------------------------------------------------------------------------
// GQA attention, inverted mask: valid(q,k) = (k>q) || (k<=q-1024).
// No-max exp2-domain softmax (logits bounded ~|14|: exp2 safe in f32).
// Computes S^T = K·Q^T so the C-layout (lane=q-col, k=quad*4+r) IS the
// B-frag layout of mfma_f32_16x16x16bf16 -> P^T feeds PV from registers,
// no LDS round-trip, no shuffles.  O^T = V^T·P^T.
// 8 waves = 2 k-split groups x 4 waves; wave owns 32 q-rows (Q in registers);
// block owns 128 q-rows; grid 16qt x 16hq = 256 = 1 block/CU.
// Groups add-merge (O, l) in LDS at the end; sink folded into denominator.
// ---------------------------------------------------------------------------
__global__ __launch_bounds__(512, 2) void attn_kernel(const bf16* __restrict__ Qb,
                                                      const bf16* __restrict__ Kb,
                                                      const bf16* __restrict__ Vtb,
                                                      const float* __restrict__ sink,
                                                      bf16* __restrict__ Ob) {
    __shared__ __align__(1024) char smem[68608];

    const int bid = blockIdx.x;
    const int t  = bid & 15;                 // 128-row q-tile
    const int hq = bid >> 4;
    const int h = hq >> 2;
    const int q0 = t * 128;
    const int tid = threadIdx.x;
    const int wid8 = tid >> 6;
    const int g = wid8 >> 2;                 // k-split group 0/1
    const int w = wid8 & 3;                  // wave in group: q rows w*32..+31
    const int lane = tid & 63;
    const int quad = lane >> 4, l15 = lane & 15;

    bf16* Ks  = (bf16*)(smem + g * 32768);           // 64 keys x 128 d
    bf16* Vts = (bf16*)(smem + g * 32768 + 16384);   // 128 d x 64 keys

    const bf16* Qg = Qb + (long)hq * L_SEQ * HD;
    const bf16* Kg = Kb + (long)h * L_SEQ * HD;
    const bf16* Vg = Vtb + (long)h * HD * L_SEQ;

    // Q as register B-frags (Q^T B-layout == row-major per-lane reads)
    bf16x8 qb[2][4];
#pragma unroll
    for (int rf = 0; rf < 2; ++rf)
#pragma unroll
        for (int kkd = 0; kkd < 4; ++kkd)
            qb[rf][kkd] = *(const bf16x8*)(Qg + (long)(q0 + w * 32 + rf * 16 + l15) * HD
                                              + kkd * 32 + quad * 8);

    f32x4 oaccT[2][8];
#pragma unroll
    for (int rf = 0; rf < 2; ++rf)
#pragma unroll
        for (int j = 0; j < 8; ++j) oaccT[rf][j] = (f32x4){0.f, 0.f, 0.f, 0.f};
    float lacc[2] = {0.f, 0.f};

    // valid 64-wide k-tiles: [0, 2t-15] U [2t, 31]
    const int locnt = (2 * t - 14 > 0) ? (2 * t - 14) : 0;
    const int n = locnt + 32 - 2 * t;
    const int iters = (n + 1) >> 1;

    for (int it = 0; it < iters; ++it) {
        const int i = 2 * it + g;
        const bool active = i < n;
        const int kt = (i < locnt) ? i : (2 * t + (i - locnt));
        const int k0 = kt * 64;
        __syncthreads();   // all waves done reading previous tiles
        if (active) {
#pragma unroll
            for (int ii = 0; ii < 4; ++ii) {   // K: 4 rows per GLD16
                int rowb = w * 16 + ii * 4;
                int row = rowb + quad;
                GLD16(Kg + (long)(k0 + row) * HD + ((l15 ^ (row & 7)) * 8), &Ks[rowb * 128]);
            }
#pragma unroll
            for (int ii = 0; ii < 4; ++ii) {   // V^T: 8 rows per GLD16
                int rowb = w * 32 + ii * 8;
                int row = rowb + (lane >> 3);
                GLD16(Vg + (long)row * L_SEQ + k0 + (((lane & 7) ^ (row & 7)) * 8), &Vts[rowb * 64]);
            }
        }
        __syncthreads();   // staged
        if (!active) continue;

        // S^T = K Q^T : per wave 64 keys x 32 q
        f32x4 sacc[2][4];
#pragma unroll
        for (int kb = 0; kb < 4; ++kb) {
            bf16x8 ka[4];
#pragma unroll
            for (int kkd = 0; kkd < 4; ++kkd)
                ka[kkd] = *(const bf16x8*)&Ks[(kb * 16 + l15) * 128 +
                                              (((kkd * 4 + quad) ^ (l15 & 7)) * 8)];
#pragma unroll
            for (int rf = 0; rf < 2; ++rf) {
                f32x4 acc = (f32x4){0.f, 0.f, 0.f, 0.f};
#pragma unroll
                for (int kkd = 0; kkd < 4; ++kkd)
                    acc = __builtin_amdgcn_mfma_f32_16x16x32_bf16(ka[kkd], qb[rf][kkd], acc, 0, 0, 0);
                sacc[rf][kb] = acc;
            }
        }

        // mask (boundary tiles only) + exp2 + pack P^T B-frags + l accumulate
        const bool bnd = (kt == 2 * t) || (kt == 2 * t + 1) ||
                         (kt == 2 * t - 15) || (kt == 2 * t - 16);
        s16x4 pb[2][4];
#pragma unroll
        for (int rf = 0; rf < 2; ++rf) {
            const int qq = q0 + w * 32 + rf * 16 + l15;
#pragma unroll
            for (int kb = 0; kb < 4; ++kb) {
#pragma unroll
                for (int r = 0; r < 4; ++r) {
                    float v = sacc[rf][kb][r];
                    if (bnd) {
                        const int kk = k0 + kb * 16 + quad * 4 + r;
                        if (!((kk > qq) || (kk <= qq - 1024))) v = -1e30f;
                    }
                    const float p = exp2f(v);
                    lacc[rf] += p;
                    bf16 hp = (bf16)p;
                    pb[rf][kb][r] = __builtin_bit_cast(short, hp);
                }
            }
        }

        // O^T += V^T P^T : 16x16x16 MFMA, A = V^T b64 reads, B = pb (registers)
#pragma unroll
        for (int j = 0; j < 8; ++j) {
            const int drow = j * 16 + l15;
#pragma unroll
            for (int kq = 0; kq < 4; ++kq) {
                const int pc = ((kq * 2 + (quad >> 1)) ^ (l15 & 7));
                s16x4 va = *(const s16x4*)((const char*)&Vts[drow * 64] + pc * 16 + (quad & 1) * 8);
#pragma unroll
                for (int rf = 0; rf < 2; ++rf)
                    oaccT[rf][j] = __builtin_amdgcn_mfma_f32_16x16x16bf16_1k(
                        va, pb[rf][kq], oaccT[rf][j], 0, 0, 0);
            }
        }
    }

    // reduce l across quads (k = quad*4+r spans quads)
#pragma unroll
    for (int rf = 0; rf < 2; ++rf) {
        lacc[rf] += __shfl_xor(lacc[rf], 16, 64);
        lacc[rf] += __shfl_xor(lacc[rf], 32, 64);
    }

    // ---------------- merge the two groups (simple add) ----------------
    __syncthreads();                      // staging regions now dead
    float* Obuf = (float*)smem;           // [128][132] f32
    float* lbuf = (float*)(smem + 67584); // [128]
    if (g == 1) {
#pragma unroll
        for (int rf = 0; rf < 2; ++rf) {
            const int ql = w * 32 + rf * 16 + l15;
#pragma unroll
            for (int j = 0; j < 8; ++j)
                *(f32x4*)&Obuf[ql * 132 + j * 16 + quad * 4] = oaccT[rf][j];
            if (quad == 0) lbuf[ql] = lacc[rf];
        }
    }
    __syncthreads();
    if (g == 0) {
        const float sv2 = sink[hq] * LOG2E;
#pragma unroll
        for (int rf = 0; rf < 2; ++rf) {
            const int ql = w * 32 + rf * 16 + l15;
            const float ltot = lacc[rf] + lbuf[ql] + exp2f(sv2);
            const float inv = 1.0f / ltot;
            bf16* dst = Ob + (long)(q0 + ql) * D_MODEL + hq * HD;
#pragma unroll
            for (int j = 0; j < 8; ++j) {
                f32x4 o2 = *(const f32x4*)&Obuf[ql * 132 + j * 16 + quad * 4];
                bf16x4v ov;
#pragma unroll
                for (int r = 0; r < 4; ++r)
                    ov[r] = (bf16)((oaccT[rf][j][r] + o2[r]) * inv);
                *(bf16x4v*)(dst + j * 16 + quad * 4) = ov;
            }
        }
    }
}

// ---------------------------------------------------------------------------
extern "C" void kernel_launch(void* const* d_in, const int* in_sizes, int n_in,
                              void* d_out, int out_size, void* d_ws, size_t ws_size,
                              hipStream_t stream) {
    (void)in_sizes; (void)n_in; (void)out_size; (void)ws_size;
    const float* x    = (const float*)d_in[0];
    const float* Wqkv = (const float*)d_in[1];
    const float* Wo   = (const float*)d_in[2];
    const float* s    = (const float*)d_in[3];
    float* out = (float*)d_out;

    char* ws = (char*)d_ws;
    bf16* xb    = (bf16*)ws;  ws += (size_t)D_MODEL * D_MODEL * 2;
    bf16* wqkvT = (bf16*)ws;  ws += (size_t)QKV_N * D_MODEL * 2;
    bf16* woT   = (bf16*)ws;  ws += (size_t)D_MODEL * D_MODEL * 2;
    bf16* Qb    = (bf16*)ws;  ws += (size_t)16 * L_SEQ * HD * 2;
    bf16* Kb    = (bf16*)ws;  ws += (size_t)4 * L_SEQ * HD * 2;
    bf16* Vtb   = (bf16*)ws;  ws += (size_t)4 * HD * L_SEQ * 2;
    bf16* attnb = (bf16*)ws;  ws += (size_t)L_SEQ * D_MODEL * 2;
    bf16* projb = (bf16*)ws;  ws += (size_t)L_SEQ * QKV_N * 2;

    cast_f32_bf16<<<(D_MODEL * D_MODEL) / 1024, 256, 0, stream>>>(x, xb, D_MODEL * D_MODEL);
    transpose_cast<<<dim3(QKV_N / 32, D_MODEL / 32, 1), dim3(32, 8), 0, stream>>>(
        Wqkv, QKV_N, wqkvT, D_MODEL, 0, 0);
    transpose_cast<<<dim3(D_MODEL / 32, D_MODEL / 32, 1), dim3(32, 8), 0, stream>>>(
        Wo, D_MODEL, woT, D_MODEL, 0, 0);

    gemm_bt<bf16><<<dim3(QKV_N / 128, L_SEQ / 128), 256, 0, stream>>>(
        xb, wqkvT, projb, L_SEQ, QKV_N, D_MODEL);

    rope_split<<<(L_SEQ * 20 * 64) / 256, 256, 0, stream>>>(projb, Qb, Kb);
    transpose_b<<<dim3(HD / 32, L_SEQ / 32, 4), dim3(32, 8), 0, stream>>>(
        projb + 2560, QKV_N, Vtb, L_SEQ, 128, (long)HD * L_SEQ);

    attn_kernel<<<256, 512, 0, stream>>>(Qb, Kb, Vtb, s, attnb);

    gemm_bt<float><<<dim3(D_MODEL / 128, L_SEQ / 128), 256, 0, stream>>>(
        attnb, woT, out, L_SEQ, D_MODEL, D_MODEL);
}

// Round 5
// 244.507 us; speedup vs baseline: 1.6126x; 1.1336x over previous
//
#include <hip/hip_runtime.h>
#include <hip/hip_bf16.h>
#include <math.h>

typedef __bf16 bf16;
typedef __bf16 bf16x8 __attribute__((ext_vector_type(8)));
typedef __bf16 bf16x4v __attribute__((ext_vector_type(4)));
typedef short s16x4 __attribute__((ext_vector_type(4)));
typedef float f32x4 __attribute__((ext_vector_type(4)));

#define GLD16(gp, lp) __builtin_amdgcn_global_load_lds( \
    (__attribute__((address_space(1))) void*)(void*)(gp), \
    (__attribute__((address_space(3))) void*)(lp), 16, 0, 0)

#define L_SEQ 2048
#define D_MODEL 2048
#define QKV_N 3072
#define HD 128
#define QSCALE 0.1275310242959836f               // (1/sqrt(128)) * log2(e)
#define LOG2E 1.4426950408889634f

// ---------------------------------------------------------------------------
// prep: fused  (a) x f32->bf16 cast  (b) Wqkv^T cast  (c) Wo^T cast
// grid = 4096 (cast) + 6144 (Wqkv 96x64 tiles) + 4096 (Wo 64x64 tiles)
// ---------------------------------------------------------------------------
__global__ __launch_bounds__(256) void prep(const float* __restrict__ x,
                                            const float* __restrict__ Wqkv,
                                            const float* __restrict__ Wo,
                                            bf16* __restrict__ xb,
                                            bf16* __restrict__ wqkvT,
                                            bf16* __restrict__ woT) {
    __shared__ float tile[32][33];
    int bid = blockIdx.x;
    if (bid < 4096) {                       // cast x (4M elems, 4/thread)
        int idx = (bid * 256 + threadIdx.x) * 4;
        float4 f = *(const float4*)(x + idx);
        bf16x4v o;
        o.x = (bf16)f.x; o.y = (bf16)f.y; o.z = (bf16)f.z; o.w = (bf16)f.w;
        *(bf16x4v*)(xb + idx) = o;
        return;
    }
    bid -= 4096;
    const float* src; bf16* dst; long ld_s, ld_d; int bx, by;
    if (bid < 6144) { bx = bid % 96; by = bid / 96; src = Wqkv; dst = wqkvT; ld_s = QKV_N; ld_d = D_MODEL; }
    else { bid -= 6144; bx = bid & 63; by = bid >> 6; src = Wo; dst = woT; ld_s = D_MODEL; ld_d = D_MODEL; }
    const int tx = threadIdx.x & 31, ty = threadIdx.x >> 5;
    const long c = bx * 32 + tx, r0 = by * 32;
#pragma unroll
    for (int i = 0; i < 4; ++i)
        tile[ty + i * 8][tx] = src[(r0 + ty + i * 8) * ld_s + c];
    __syncthreads();
    const long c0 = bx * 32;
#pragma unroll
    for (int i = 0; i < 4; ++i)
        dst[(c0 + ty + i * 8) * ld_d + r0 + tx] = (bf16)tile[tx][ty + i * 8];
}

// ---------------------------------------------------------------------------
// GEMM1 fused: proj = xb @ WqkvT, with RoPE + split + V-transpose epilogue.
// 128x128 tile; col-tile bx IS one head (Q:0-15, K:16-19, V:20-23).
// Wave cols remapped to j*32 + wn*16 + l15 so the RoPE pair (d, d+64) is
// (acc[i][0],acc[i][2]) in-lane; j=0 rotates (d<32), j=1/3 are identity.
// Writes Qb (scaled by QSCALE), Kb, and V^T[h][d][l] directly; no proj buffer.
// ---------------------------------------------------------------------------
__global__ __launch_bounds__(256) void gemm_qkv(const bf16* __restrict__ A,
                                                const bf16* __restrict__ Bt,
                                                bf16* __restrict__ Qb,
                                                bf16* __restrict__ Kb,
                                                bf16* __restrict__ Vtb) {
    constexpr int K = D_MODEL;
    __shared__ __align__(16) bf16 As[128 * 32];
    __shared__ __align__(16) bf16 Bs[128 * 32];
    const int tid = threadIdx.x;
    const int wid = tid >> 6, lane = tid & 63;
    const int quad = lane >> 4, l15 = lane & 15;
    const int wm = wid & 1, wn = wid >> 1;
    const int head = blockIdx.x;
    const long m0 = (long)blockIdx.y * 128, n0 = (long)head * 128;

    const int srow = wid * 32 + (lane >> 2);
    const int scol = ((lane & 3) ^ ((lane >> 3) & 3)) * 8;

    f32x4 acc[4][4];
#pragma unroll
    for (int i = 0; i < 4; ++i)
#pragma unroll
        for (int j = 0; j < 4; ++j) acc[i][j] = (f32x4){0.f, 0.f, 0.f, 0.f};

    const bf16* Ap  = A  + (m0 + srow) * K + scol;
    const bf16* Ap2 = Ap + (long)16 * K;
    const bf16* Bp  = Bt + (n0 + srow) * K + scol;
    const bf16* Bp2 = Bp + (long)16 * K;
    bf16* lA  = &As[(wid * 32) * 32];
    bf16* lA2 = &As[(wid * 32 + 16) * 32];
    bf16* lB  = &Bs[(wid * 32) * 32];
    bf16* lB2 = &Bs[(wid * 32 + 16) * 32];

    const int rsw = ((l15 >> 1) & 3);

    for (int k0 = 0; k0 < K; k0 += 32) {
        GLD16(Ap + k0, lA);
        GLD16(Ap2 + k0, lA2);
        GLD16(Bp + k0, lB);
        GLD16(Bp2 + k0, lB2);
        __syncthreads();
        bf16x8 af[4], bfr[4];
#pragma unroll
        for (int i = 0; i < 4; ++i)
            af[i] = *(const bf16x8*)&As[(wm * 64 + i * 16 + l15) * 32 + (quad ^ rsw) * 8];
#pragma unroll
        for (int j = 0; j < 4; ++j)
            bfr[j] = *(const bf16x8*)&Bs[(j * 32 + wn * 16 + l15) * 32 + (quad ^ rsw) * 8];
#pragma unroll
        for (int i = 0; i < 4; ++i)
#pragma unroll
            for (int j = 0; j < 4; ++j)
                acc[i][j] = __builtin_amdgcn_mfma_f32_16x16x32_bf16(af[i], bfr[j], acc[i][j], 0, 0, 0);
        __syncthreads();
    }

    const int d0 = wn * 16 + l15;                      // 0..31
    if (head < 20) {                                   // Q or K head: RoPE
        const float freq = exp2f((float)d0 * (-10.0f / 31.0f));
        const float sc = head < 16 ? QSCALE : 1.0f;
        bf16* dst = head < 16 ? Qb + (long)head * L_SEQ * HD
                              : Kb + (long)(head - 16) * L_SEQ * HD;
#pragma unroll
        for (int i = 0; i < 4; ++i) {
            const long mb = m0 + wm * 64 + i * 16 + quad * 4;
#pragma unroll
            for (int r = 0; r < 4; ++r) {
                const long row = mb + r;
                float sn, cs;
                sincosf((float)row * freq, &sn, &cs);
                const float x1 = acc[i][0][r], x2 = acc[i][2][r];
                bf16* p = dst + row * HD + d0;
                p[0]  = (bf16)((x1 * cs + x2 * sn) * sc);
                p[64] = (bf16)((x2 * cs - x1 * sn) * sc);
                p[32] = (bf16)(acc[i][1][r] * sc);
                p[96] = (bf16)(acc[i][3][r] * sc);
            }
        }
    } else {                                           // V head: write V^T[d][l]
        bf16* dst = Vtb + (long)(head - 20) * HD * L_SEQ;
#pragma unroll
        for (int i = 0; i < 4; ++i) {
            const long m = m0 + wm * 64 + i * 16 + quad * 4;
#pragma unroll
            for (int j = 0; j < 4; ++j) {
                const int d = j * 32 + d0;
                bf16x4v vv;
#pragma unroll
                for (int r = 0; r < 4; ++r) vv[r] = (bf16)acc[i][j][r];
                *(bf16x4v*)(dst + (long)d * L_SEQ + m) = vv;
            }
        }
    }
}

// ---------------------------------------------------------------------------
// GEMM2: out f32 = attnb bf16 @ woT.  (m97 structure, swizzled LDS.)
// ---------------------------------------------------------------------------
__global__ __launch_bounds__(256) void gemm_bt(const bf16* __restrict__ A,
                                               const bf16* __restrict__ Bt,
                                               float* __restrict__ C,
                                               int M, int N, int K) {
    __shared__ __align__(16) bf16 As[128 * 32];
    __shared__ __align__(16) bf16 Bs[128 * 32];
    const int tid = threadIdx.x;
    const int wid = tid >> 6, lane = tid & 63;
    const int quad = lane >> 4, l15 = lane & 15;
    const int wm = wid & 1, wn = wid >> 1;
    const long m0 = (long)blockIdx.y * 128, n0 = (long)blockIdx.x * 128;

    const int srow = wid * 32 + (lane >> 2);
    const int scol = ((lane & 3) ^ ((lane >> 3) & 3)) * 8;

    f32x4 acc[4][4];
#pragma unroll
    for (int i = 0; i < 4; ++i)
#pragma unroll
        for (int j = 0; j < 4; ++j) acc[i][j] = (f32x4){0.f, 0.f, 0.f, 0.f};

    const bf16* Ap  = A  + (m0 + srow) * K + scol;
    const bf16* Ap2 = Ap + (long)16 * K;
    const bf16* Bp  = Bt + (n0 + srow) * K + scol;
    const bf16* Bp2 = Bp + (long)16 * K;
    bf16* lA  = &As[(wid * 32) * 32];
    bf16* lA2 = &As[(wid * 32 + 16) * 32];
    bf16* lB  = &Bs[(wid * 32) * 32];
    bf16* lB2 = &Bs[(wid * 32 + 16) * 32];

    const int rsw = ((l15 >> 1) & 3);

    for (int k0 = 0; k0 < K; k0 += 32) {
        GLD16(Ap + k0, lA);
        GLD16(Ap2 + k0, lA2);
        GLD16(Bp + k0, lB);
        GLD16(Bp2 + k0, lB2);
        __syncthreads();
        bf16x8 af[4], bfr[4];
#pragma unroll
        for (int i = 0; i < 4; ++i)
            af[i] = *(const bf16x8*)&As[(wm * 64 + i * 16 + l15) * 32 + (quad ^ rsw) * 8];
#pragma unroll
        for (int j = 0; j < 4; ++j)
            bfr[j] = *(const bf16x8*)&Bs[(wn * 64 + j * 16 + l15) * 32 + (quad ^ rsw) * 8];
#pragma unroll
        for (int i = 0; i < 4; ++i)
#pragma unroll
            for (int j = 0; j < 4; ++j)
                acc[i][j] = __builtin_amdgcn_mfma_f32_16x16x32_bf16(af[i], bfr[j], acc[i][j], 0, 0, 0);
        __syncthreads();
    }
#pragma unroll
    for (int i = 0; i < 4; ++i)
#pragma unroll
        for (int j = 0; j < 4; ++j) {
            long m = m0 + wm * 64 + i * 16 + quad * 4;
            long n = n0 + wn * 64 + j * 16 + l15;
#pragma unroll
            for (int r = 0; r < 4; ++r)
                C[(m + r) * (long)N + n] = acc[i][j][r];
        }
}

// ---------------------------------------------------------------------------
// GQA attention (inverted mask, no-max exp2 softmax, S^T trick) with
// DOUBLE-BUFFERED staging: one barrier per k-tile; stage(i+1) issued right
// after the barrier, compute(i) overlaps the global->LDS DMA.
// LDS = 2 groups x 2 bufs x (K 16KB + V^T 16KB) = 128 KB; 1 block/CU.
// ---------------------------------------------------------------------------
__global__ __launch_bounds__(512, 2) void attn_kernel(const bf16* __restrict__ Qb,
                                                      const bf16* __restrict__ Kb,
                                                      const bf16* __restrict__ Vtb,
                                                      const float* __restrict__ sink,
                                                      bf16* __restrict__ Ob) {
    __shared__ __align__(1024) char smem[131072];

    const int bid = blockIdx.x;
    const int t  = bid & 15;                 // 128-row q-tile
    const int hq = bid >> 4;
    const int h = hq >> 2;
    const int q0 = t * 128;
    const int tid = threadIdx.x;
    const int wid8 = tid >> 6;
    const int g = wid8 >> 2;                 // k-split group 0/1
    const int w = wid8 & 3;                  // wave in group
    const int lane = tid & 63;
    const int quad = lane >> 4, l15 = lane & 15;

    const bf16* Qg = Qb + (long)hq * L_SEQ * HD;
    const bf16* Kg = Kb + (long)h * L_SEQ * HD;
    const bf16* Vg = Vtb + (long)h * HD * L_SEQ;

    // Q as register B-frags
    bf16x8 qb[2][4];
#pragma unroll
    for (int rf = 0; rf < 2; ++rf)
#pragma unroll
        for (int kkd = 0; kkd < 4; ++kkd)
            qb[rf][kkd] = *(const bf16x8*)(Qg + (long)(q0 + w * 32 + rf * 16 + l15) * HD
                                              + kkd * 32 + quad * 8);

    f32x4 oaccT[2][8];
#pragma unroll
    for (int rf = 0; rf < 2; ++rf)
#pragma unroll
        for (int j = 0; j < 8; ++j) oaccT[rf][j] = (f32x4){0.f, 0.f, 0.f, 0.f};
    float lacc[2] = {0.f, 0.f};

    // valid 64-wide k-tiles: [0, 2t-15] U [2t, 31]
    const int locnt = (2 * t - 14 > 0) ? (2 * t - 14) : 0;
    const int n = locnt + 32 - 2 * t;
    const int iters = (n + 1) >> 1;

    auto stage = [&](int it2, int buf) {
        const int i = 2 * it2 + g;
        if (i >= n) return;
        const int kt = (i < locnt) ? i : (2 * t + (i - locnt));
        const int k0 = kt * 64;
        bf16* Ksb  = (bf16*)(smem + g * 65536 + buf * 32768);
        bf16* Vtsb = (bf16*)(smem + g * 65536 + buf * 32768 + 16384);
#pragma unroll
        for (int ii = 0; ii < 4; ++ii) {     // K tile: 64 keys x 128 d
            int rowb = w * 16 + ii * 4;
            int row = rowb + quad;
            GLD16(Kg + (long)(k0 + row) * HD + ((l15 ^ (row & 7)) * 8), &Ksb[rowb * 128]);
        }
#pragma unroll
        for (int ii = 0; ii < 4; ++ii) {     // V^T tile: 128 d x 64 keys
            int rowb = w * 32 + ii * 8;
            int row = rowb + (lane >> 3);
            GLD16(Vg + (long)row * L_SEQ + k0 + (((lane & 7) ^ (row & 7)) * 8), &Vtsb[rowb * 64]);
        }
    };

    stage(0, 0);

    for (int it = 0; it < iters; ++it) {
        __syncthreads();                     // drains stage(it); prev reads done
        if (it + 1 < iters) stage(it + 1, (it + 1) & 1);

        const int i = 2 * it + g;
        if (i >= n) continue;
        const int kt = (i < locnt) ? i : (2 * t + (i - locnt));
        const int k0 = kt * 64;
        const bf16* Ks  = (const bf16*)(smem + g * 65536 + (it & 1) * 32768);
        const bf16* Vts = (const bf16*)(smem + g * 65536 + (it & 1) * 32768 + 16384);

        // S^T = K Q^T : per wave 64 keys x 32 q
        f32x4 sacc[2][4];
#pragma unroll
        for (int kb = 0; kb < 4; ++kb) {
            bf16x8 ka[4];
#pragma unroll
            for (int kkd = 0; kkd < 4; ++kkd)
                ka[kkd] = *(const bf16x8*)&Ks[(kb * 16 + l15) * 128 +
                                              (((kkd * 4 + quad) ^ (l15 & 7)) * 8)];
#pragma unroll
            for (int rf = 0; rf < 2; ++rf) {
                f32x4 acc = (f32x4){0.f, 0.f, 0.f, 0.f};
#pragma unroll
                for (int kkd = 0; kkd < 4; ++kkd)
                    acc = __builtin_amdgcn_mfma_f32_16x16x32_bf16(ka[kkd], qb[rf][kkd], acc, 0, 0, 0);
                sacc[rf][kb] = acc;
            }
        }

        // mask boundary tiles + exp2 + pack P^T B-frags + l accumulate
        const bool bnd = (kt == 2 * t) || (kt == 2 * t + 1) ||
                         (kt == 2 * t - 15) || (kt == 2 * t - 16);
        s16x4 pb[2][4];
#pragma unroll
        for (int rf = 0; rf < 2; ++rf) {
            const int qq = q0 + w * 32 + rf * 16 + l15;
#pragma unroll
            for (int kb = 0; kb < 4; ++kb) {
#pragma unroll
                for (int r = 0; r < 4; ++r) {
                    float v = sacc[rf][kb][r];
                    if (bnd) {
                        const int kk = k0 + kb * 16 + quad * 4 + r;
                        if (!((kk > qq) || (kk <= qq - 1024))) v = -1e30f;
                    }
                    const float p = exp2f(v);
                    lacc[rf] += p;
                    bf16 hp = (bf16)p;
                    pb[rf][kb][r] = __builtin_bit_cast(short, hp);
                }
            }
        }

        // O^T += V^T P^T : 16x16x16 MFMA, A from LDS, B from registers
#pragma unroll
        for (int j = 0; j < 8; ++j) {
            const int drow = j * 16 + l15;
#pragma unroll
            for (int kq = 0; kq < 4; ++kq) {
                const int pc = ((kq * 2 + (quad >> 1)) ^ (l15 & 7));
                s16x4 va = *(const s16x4*)((const char*)&Vts[drow * 64] + pc * 16 + (quad & 1) * 8);
#pragma unroll
                for (int rf = 0; rf < 2; ++rf)
                    oaccT[rf][j] = __builtin_amdgcn_mfma_f32_16x16x16bf16_1k(
                        va, pb[rf][kq], oaccT[rf][j], 0, 0, 0);
            }
        }
    }

    // reduce l across quads
#pragma unroll
    for (int rf = 0; rf < 2; ++rf) {
        lacc[rf] += __shfl_xor(lacc[rf], 16, 64);
        lacc[rf] += __shfl_xor(lacc[rf], 32, 64);
    }

    // ---------------- merge the two groups (simple add) ----------------
    __syncthreads();                      // staging regions now dead
    float* Obuf = (float*)smem;           // [128][132] f32
    float* lbuf = (float*)(smem + 67584); // [128]
    if (g == 1) {
#pragma unroll
        for (int rf = 0; rf < 2; ++rf) {
            const int ql = w * 32 + rf * 16 + l15;
#pragma unroll
            for (int j = 0; j < 8; ++j)
                *(f32x4*)&Obuf[ql * 132 + j * 16 + quad * 4] = oaccT[rf][j];
            if (quad == 0) lbuf[ql] = lacc[rf];
        }
    }
    __syncthreads();
    if (g == 0) {
        const float sv2 = sink[hq] * LOG2E;
#pragma unroll
        for (int rf = 0; rf < 2; ++rf) {
            const int ql = w * 32 + rf * 16 + l15;
            const float ltot = lacc[rf] + lbuf[ql] + exp2f(sv2);
            const float inv = 1.0f / ltot;
            bf16* dst = Ob + (long)(q0 + ql) * D_MODEL + hq * HD;
#pragma unroll
            for (int j = 0; j < 8; ++j) {
                f32x4 o2 = *(const f32x4*)&Obuf[ql * 132 + j * 16 + quad * 4];
                bf16x4v ov;
#pragma unroll
                for (int r = 0; r < 4; ++r)
                    ov[r] = (bf16)((oaccT[rf][j][r] + o2[r]) * inv);
                *(bf16x4v*)(dst + j * 16 + quad * 4) = ov;
            }
        }
    }
}

// ---------------------------------------------------------------------------
extern "C" void kernel_launch(void* const* d_in, const int* in_sizes, int n_in,
                              void* d_out, int out_size, void* d_ws, size_t ws_size,
                              hipStream_t stream) {
    (void)in_sizes; (void)n_in; (void)out_size; (void)ws_size;
    const float* x    = (const float*)d_in[0];
    const float* Wqkv = (const float*)d_in[1];
    const float* Wo   = (const float*)d_in[2];
    const float* s    = (const float*)d_in[3];
    float* out = (float*)d_out;

    char* ws = (char*)d_ws;
    bf16* xb    = (bf16*)ws;  ws += (size_t)D_MODEL * D_MODEL * 2;
    bf16* wqkvT = (bf16*)ws;  ws += (size_t)QKV_N * D_MODEL * 2;
    bf16* woT   = (bf16*)ws;  ws += (size_t)D_MODEL * D_MODEL * 2;
    bf16* Qb    = (bf16*)ws;  ws += (size_t)16 * L_SEQ * HD * 2;
    bf16* Kb    = (bf16*)ws;  ws += (size_t)4 * L_SEQ * HD * 2;
    bf16* Vtb   = (bf16*)ws;  ws += (size_t)4 * HD * L_SEQ * 2;
    bf16* attnb = (bf16*)ws;  ws += (size_t)L_SEQ * D_MODEL * 2;

    prep<<<14336, 256, 0, stream>>>(x, Wqkv, Wo, xb, wqkvT, woT);

    gemm_qkv<<<dim3(QKV_N / 128, L_SEQ / 128), 256, 0, stream>>>(
        xb, wqkvT, Qb, Kb, Vtb);

    attn_kernel<<<256, 512, 0, stream>>>(Qb, Kb, Vtb, s, attnb);

    gemm_bt<<<dim3(D_MODEL / 128, L_SEQ / 128), 256, 0, stream>>>(
        attnb, woT, out, L_SEQ, D_MODEL, D_MODEL);
}